// Round 15
// baseline (717.653 us; speedup 1.0000x reference)
//
#include <hip/hip_runtime.h>
#include <math.h>

// ---------------------------------------------------------------------------
// GraphAutoEncoder forward on MI355X. Round 15 = round 14 plus:
//   - GEMM0 reads f32 x directly, converting to hi/lo fp16 in registers
//     (each A-row read exactly once across blocks -> conversion is free;
//     kills conv_x dispatch + 124MB of plane write/re-read traffic)
//   - GAT: dual-state online softmax (two independent m/s/acc chains on
//     alternating 4-edge batches, exact merge) -> halves the serial
//     rescale dependency of the VALU-bound loop
//   - single-plane fp16 weights, int2 CSR, hf8 props unchanged
// ---------------------------------------------------------------------------

typedef __attribute__((ext_vector_type(4))) float f32x4;
typedef _Float16 hf2 __attribute__((ext_vector_type(2)));
typedef _Float16 hf4 __attribute__((ext_vector_type(4)));
typedef _Float16 hf8 __attribute__((ext_vector_type(8)));

// ---------------- CSR build ----------------

__global__ void deg_kernel(const int* __restrict__ ei, int* __restrict__ deg, int E) {
  int i = blockIdx.x * blockDim.x + threadIdx.x;
  int stride = gridDim.x * blockDim.x;
  for (; i < E; i += stride) atomicAdd(&deg[ei[E + i]], 1);
}

__global__ void dinv_kernel(const int* __restrict__ deg, float* __restrict__ dinv,
                            int* __restrict__ rowptr, int N) {
  int i = blockIdx.x * blockDim.x + threadIdx.x;
  if (i == 0) rowptr[0] = 0;
  if (i < N) dinv[i] = rsqrtf((float)(deg[i] + 1));  // +1 self-loop
}

__global__ __launch_bounds__(256) void scan_block_kernel(const int* __restrict__ in,
                                                         int* __restrict__ out,
                                                         int* __restrict__ bsum, int n) {
  __shared__ int lds[256];
  const int base = blockIdx.x * 2048;
  const int tid = threadIdx.x;
  int v[8];
  int s = 0;
#pragma unroll
  for (int k = 0; k < 8; ++k) {
    int idx = base + tid * 8 + k;
    v[k] = (idx < n) ? in[idx] : 0;
    s += v[k];
  }
  lds[tid] = s;
  __syncthreads();
  for (int off = 1; off < 256; off <<= 1) {
    int t = (tid >= off) ? lds[tid - off] : 0;
    __syncthreads();
    lds[tid] += t;
    __syncthreads();
  }
  int run = (tid > 0) ? lds[tid - 1] : 0;
#pragma unroll
  for (int k = 0; k < 8; ++k) {
    int idx = base + tid * 8 + k;
    run += v[k];
    if (idx < n) out[idx] = run;
  }
  if (tid == 255) bsum[blockIdx.x] = lds[255];
}

__global__ void scan_small_kernel(int* bsum, int nb) {
  if (threadIdx.x == 0 && blockIdx.x == 0) {
    int run = 0;
    for (int i = 0; i < nb; ++i) { int t = bsum[i]; bsum[i] = run; run += t; }
  }
}

__global__ __launch_bounds__(256) void scan_add_kernel(int* __restrict__ out,
                                                       const int* __restrict__ bsum, int n) {
  int idx = blockIdx.x * 2048 + threadIdx.x;
  const int add = bsum[blockIdx.x];
#pragma unroll
  for (int k = 0; k < 8; ++k, idx += 256)
    if (idx < n) out[idx] += add;
}

// one random 8B store per edge (col + val bits packed)
__global__ void fill_csr_kernel(const int* __restrict__ ei, const float* __restrict__ dinv,
                                const int* __restrict__ rowptr, int* __restrict__ fill,
                                int2* __restrict__ ecv, int E) {
  int e = blockIdx.x * blockDim.x + threadIdx.x;
  int stride = gridDim.x * blockDim.x;
  for (; e < E; e += stride) {
    int s = ei[e], t = ei[E + e];
    int pos = rowptr[t] + atomicAdd(&fill[t], 1);
    ecv[pos] = make_int2(s, __float_as_int(dinv[s] * dinv[t]));
  }
}

// ---------------- propagation (CSR gather hf8, f32 accumulate) -------------
// EPI: 0 none | 1 +bias(f32) | 2 relu(+bias f32) | 3 0.5*acc+0.5*bx16
// OUT: 1 = f32 out | 4 = fp16 pf.  OS = output row stride in hf8 units.
// PAD: write zero hf8 at pf[node*OS + TPN + q] (layer-4 Kp pad)
template <int D, int EPI, int OUT, int OS, int PAD>
__global__ __launch_bounds__(256) void prop_csr_kernel(
    const hf8* __restrict__ h, const int* __restrict__ rowptr,
    const int2* __restrict__ ecv, const float* __restrict__ dinv,
    const float* __restrict__ bias, const hf8* __restrict__ bx16,
    float4* __restrict__ out, hf8* __restrict__ pf, int N) {
  constexpr int TPN = D / 8;
  constexpr int NPB = 256 / TPN;
  const int node = blockIdx.x * NPB + threadIdx.x / TPN;
  const int q = threadIdx.x % TPN;
  if (node >= N) return;
  const int start = rowptr[node], end = rowptr[node + 1];
  float acc[8] = {};
  int j = start;
  for (; j + 1 < end; j += 2) {
    const int2 e0 = ecv[j], e1 = ecv[j + 1];
    const float v0 = __int_as_float(e0.y), v1 = __int_as_float(e1.y);
    const hf8 a = h[(long long)e0.x * TPN + q];
    const hf8 b = h[(long long)e1.x * TPN + q];
#pragma unroll
    for (int k = 0; k < 8; ++k) acc[k] += v0 * (float)a[k] + v1 * (float)b[k];
  }
  if (j < end) {
    const int2 e0 = ecv[j];
    const float v = __int_as_float(e0.y);
    const hf8 a = h[(long long)e0.x * TPN + q];
#pragma unroll
    for (int k = 0; k < 8; ++k) acc[k] += v * (float)a[k];
  }
  {
    const float di = dinv[node];
    const float sv = di * di;
    const hf8 a = h[(long long)node * TPN + q];
#pragma unroll
    for (int k = 0; k < 8; ++k) acc[k] += sv * (float)a[k];
  }
  float r[8];
  if (EPI == 0) {
#pragma unroll
    for (int k = 0; k < 8; ++k) r[k] = acc[k];
  } else if (EPI == 1 || EPI == 2) {
    float4 b0 = ((const float4*)bias)[2 * q];
    float4 b1 = ((const float4*)bias)[2 * q + 1];
    r[0] = acc[0] + b0.x; r[1] = acc[1] + b0.y; r[2] = acc[2] + b0.z; r[3] = acc[3] + b0.w;
    r[4] = acc[4] + b1.x; r[5] = acc[5] + b1.y; r[6] = acc[6] + b1.z; r[7] = acc[7] + b1.w;
    if (EPI == 2) {
#pragma unroll
      for (int k = 0; k < 8; ++k) r[k] = fmaxf(r[k], 0.f);
    }
  } else {  // EPI == 3
    hf8 x0 = bx16[(long long)node * TPN + q];
#pragma unroll
    for (int k = 0; k < 8; ++k) r[k] = 0.5f * (acc[k] + (float)x0[k]);
  }
  if (OUT == 1) {
    float4 o0 = make_float4(r[0], r[1], r[2], r[3]);
    float4 o1 = make_float4(r[4], r[5], r[6], r[7]);
    out[(long long)node * (D / 4) + 2 * q] = o0;
    out[(long long)node * (D / 4) + 2 * q + 1] = o1;
  } else {
    hf8 p;
#pragma unroll
    for (int k = 0; k < 8; ++k) p[k] = (_Float16)r[k];
    pf[(long long)node * OS + q] = p;
    if (PAD) {
      hf8 z = {0, 0, 0, 0, 0, 0, 0, 0};
      pf[(long long)node * OS + TPN + q] = z;
    }
  }
}

// ---------------- single-kernel weight packing (single fp16 plane) ---------
struct PackDesc {
  const float* W;
  long long off;   // arena offset (halfs)
  long long cum;   // cumulative element start
  int K, Msrc, moff, Mtot, Kp;
};
struct PackArgs {
  PackDesc d[10];
  int n;
  long long total;
};

__global__ void pack_all_kernel(PackArgs pa, _Float16* __restrict__ arena) {
  long long i = (long long)blockIdx.x * blockDim.x + threadIdx.x;
  const long long stride = (long long)gridDim.x * blockDim.x;
  for (; i < pa.total; i += stride) {
    int wi = 0;
    while (wi + 1 < pa.n && i >= pa.d[wi + 1].cum) ++wi;
    const PackDesc dd = pa.d[wi];
    long long li = i - dd.cum;          // in [0, Kp*Msrc)
    int k = (int)(li / dd.Msrc);
    int m0 = (int)(li % dd.Msrc);
    int m = dd.moff + m0;
    float v = (k < dd.K) ? dd.W[(long long)k * dd.Msrc + m0] : 0.f;
    const int MT = dd.Mtot >> 4;
    int chunkk = k >> 6, kin = k & 63;
    int s2 = (kin >> 5) & 1, kin2 = kin & 31;
    int lane = ((kin2 >> 3) << 4) | (m & 15);
    int jj = kin2 & 7, t = m >> 4;
    long long idx = ((((long long)(chunkk * MT + t) * 2 + s2) * 64 + lane) * 8 + jj);
    arena[dd.off + idx] = (_Float16)v;
  }
}

// ---------------- MFMA GEMM (f16, single-product; ASPLIT=1 -> 2-product) ---
// EPI: 0 none | 2 bias+relu | 3 relu(c1*aux + c2*acc), aux fp16
// Cf2 != nullptr: split store, cols [0,M/2) -> Cf, [M/2,M) -> Cf2 (stride M/2)
template <int MT, int EPI, int ASPLIT>
__global__ __launch_bounds__(256) void gemm_mfma_kernel(
    const _Float16* __restrict__ A, const _Float16* __restrict__ Al,
    const _Float16* __restrict__ Bhi,
    const float* __restrict__ bias, const _Float16* __restrict__ aux,
    float c1, float c2, _Float16* __restrict__ Cf, _Float16* __restrict__ Cf2,
    int N, int Kp) {
  constexpr int M = MT * 16;
  constexpr int chunk = M * 64;
  __shared__ _Float16 lds[chunk];
  const int tid = threadIdx.x;
  const int w = tid >> 6, l = tid & 63;
  const int lr = l & 15, lh = l >> 4;
  const int rowbase = blockIdx.x * 128 + w * 32;
  int r0 = rowbase + lr;      if (r0 >= N) r0 = N - 1;
  int r1 = rowbase + 16 + lr; if (r1 >= N) r1 = N - 1;

  f32x4 acc[2][MT] = {};
  const int nchunks = Kp >> 6;
  const int n16 = chunk / 8;

  for (int c = 0; c < nchunks; ++c) {
    const uint4* srcH = (const uint4*)(Bhi + (long long)c * chunk);
    __syncthreads();
    for (int i = tid; i < n16; i += 256) ((uint4*)lds)[i] = srcH[i];
    __syncthreads();
#pragma unroll
    for (int s = 0; s < 2; ++s) {
      const long long abase = (long long)c * 64 + s * 32 + lh * 8;
      hf8 a0 = *(const hf8*)(A + (long long)r0 * Kp + abase);
      hf8 a1 = *(const hf8*)(A + (long long)r1 * Kp + abase);
      hf8 a0l, a1l;
      if (ASPLIT) {
        a0l = *(const hf8*)(Al + (long long)r0 * Kp + abase);
        a1l = *(const hf8*)(Al + (long long)r1 * Kp + abase);
      }
#pragma unroll
      for (int t = 0; t < MT; ++t) {
        const int boff = ((t * 2 + s) * 64 + l) * 8;
        hf8 bh = *(const hf8*)(lds + boff);
        acc[0][t] = __builtin_amdgcn_mfma_f32_16x16x32_f16(a0, bh, acc[0][t], 0, 0, 0);
        acc[1][t] = __builtin_amdgcn_mfma_f32_16x16x32_f16(a1, bh, acc[1][t], 0, 0, 0);
        if (ASPLIT) {
          acc[0][t] = __builtin_amdgcn_mfma_f32_16x16x32_f16(a0l, bh, acc[0][t], 0, 0, 0);
          acc[1][t] = __builtin_amdgcn_mfma_f32_16x16x32_f16(a1l, bh, acc[1][t], 0, 0, 0);
        }
      }
    }
  }
  // epilogue: two 64-row halves through the same LDS buffer, coalesced stores
#pragma unroll
  for (int rt = 0; rt < 2; ++rt) {
    __syncthreads();
#pragma unroll
    for (int t = 0; t < MT; ++t) {
      const int col = t * 16 + lr;
      float b = (EPI == 2) ? bias[col] : 0.f;
#pragma unroll
      for (int j = 0; j < 4; ++j) {
        int row = rowbase + rt * 16 + lh * 4 + j;
        float v;
        if (EPI == 3) {
          int ar = row < N ? row : N - 1;
          v = fmaxf(c1 * (float)aux[(long long)ar * M + col] + c2 * acc[rt][t][j], 0.f);
        } else {
          v = acc[rt][t][j] + b;
          if (EPI == 2) v = fmaxf(v, 0.f);
        }
        lds[(w * 16 + lh * 4 + j) * M + col] = (_Float16)v;
      }
    }
    __syncthreads();
    constexpr int slots = 64 * M / 8;
    const uint4* ls = (const uint4*)lds;
    for (int i = tid; i < slots; i += 256) {
      int r = i / (M / 8);
      int c8 = i % (M / 8);
      int grow = blockIdx.x * 128 + (r >> 4) * 32 + rt * 16 + (r & 15);
      if (grow < N) {
        if (Cf2) {
          if (c8 < M / 16) *(uint4*)(Cf  + (long long)grow * (M / 2) + c8 * 8) = ls[i];
          else             *(uint4*)(Cf2 + (long long)grow * (M / 2) + (c8 - M / 16) * 8) = ls[i];
        } else {
          *(uint4*)(Cf + (long long)grow * M + c8 * 8) = ls[i];
        }
      }
    }
  }
}

// ---------------- GEMM0: A = f32 x[N x 300], in-register hi/lo split -------
template <int MT>
__global__ __launch_bounds__(256) void gemm_mfma_xf32_kernel(
    const float* __restrict__ A, const _Float16* __restrict__ Bhi,
    _Float16* __restrict__ Cf, int N, int Kp, int Ksrc) {
  constexpr int M = MT * 16;
  constexpr int chunk = M * 64;
  __shared__ _Float16 lds[chunk];
  const int tid = threadIdx.x;
  const int w = tid >> 6, l = tid & 63;
  const int lr = l & 15, lh = l >> 4;
  const int rowbase = blockIdx.x * 128 + w * 32;
  int r0 = rowbase + lr;      if (r0 >= N) r0 = N - 1;
  int r1 = rowbase + 16 + lr; if (r1 >= N) r1 = N - 1;

  f32x4 acc[2][MT] = {};
  const int nchunks = Kp >> 6;
  const int n16 = chunk / 8;

  for (int c = 0; c < nchunks; ++c) {
    const uint4* srcH = (const uint4*)(Bhi + (long long)c * chunk);
    __syncthreads();
    for (int i = tid; i < n16; i += 256) ((uint4*)lds)[i] = srcH[i];
    __syncthreads();
#pragma unroll
    for (int s = 0; s < 2; ++s) {
      const int abase = c * 64 + s * 32 + lh * 8;
      float4 z4 = make_float4(0.f, 0.f, 0.f, 0.f);
      float4 v0a = (abase + 4 <= Ksrc) ? *(const float4*)(A + (long long)r0 * Ksrc + abase) : z4;
      float4 v0b = (abase + 8 <= Ksrc) ? *(const float4*)(A + (long long)r0 * Ksrc + abase + 4) : z4;
      float4 v1a = (abase + 4 <= Ksrc) ? *(const float4*)(A + (long long)r1 * Ksrc + abase) : z4;
      float4 v1b = (abase + 8 <= Ksrc) ? *(const float4*)(A + (long long)r1 * Ksrc + abase + 4) : z4;
      float f0[8] = {v0a.x, v0a.y, v0a.z, v0a.w, v0b.x, v0b.y, v0b.z, v0b.w};
      float f1[8] = {v1a.x, v1a.y, v1a.z, v1a.w, v1b.x, v1b.y, v1b.z, v1b.w};
      hf8 a0, a0l, a1, a1l;
#pragma unroll
      for (int j = 0; j < 8; ++j) {
        a0[j] = (_Float16)f0[j]; a0l[j] = (_Float16)(f0[j] - (float)a0[j]);
        a1[j] = (_Float16)f1[j]; a1l[j] = (_Float16)(f1[j] - (float)a1[j]);
      }
#pragma unroll
      for (int t = 0; t < MT; ++t) {
        const int boff = ((t * 2 + s) * 64 + l) * 8;
        hf8 bh = *(const hf8*)(lds + boff);
        acc[0][t] = __builtin_amdgcn_mfma_f32_16x16x32_f16(a0, bh, acc[0][t], 0, 0, 0);
        acc[1][t] = __builtin_amdgcn_mfma_f32_16x16x32_f16(a1, bh, acc[1][t], 0, 0, 0);
        acc[0][t] = __builtin_amdgcn_mfma_f32_16x16x32_f16(a0l, bh, acc[0][t], 0, 0, 0);
        acc[1][t] = __builtin_amdgcn_mfma_f32_16x16x32_f16(a1l, bh, acc[1][t], 0, 0, 0);
      }
    }
  }
  // epilogue (EPI=0), two 64-row halves
#pragma unroll
  for (int rt = 0; rt < 2; ++rt) {
    __syncthreads();
#pragma unroll
    for (int t = 0; t < MT; ++t) {
      const int col = t * 16 + lr;
#pragma unroll
      for (int j = 0; j < 4; ++j)
        lds[(w * 16 + lh * 4 + j) * M + col] = (_Float16)acc[rt][t][j];
    }
    __syncthreads();
    constexpr int slots = 64 * M / 8;
    const uint4* ls = (const uint4*)lds;
    for (int i = tid; i < slots; i += 256) {
      int r = i / (M / 8);
      int c8 = i % (M / 8);
      int grow = blockIdx.x * 128 + (r >> 4) * 32 + rt * 16 + (r & 15);
      if (grow < N) *(uint4*)(Cf + (long long)grow * M + c8 * 8) = ls[i];
    }
  }
}

// ---------------- fused GATv2 (dual-state online softmax, 2 nodes/wave) ----
__global__ __launch_bounds__(256) void gat_fused_kernel(
    const hf4* __restrict__ xl, const hf4* __restrict__ xr,
    const float* __restrict__ att, const int* __restrict__ rowptr,
    const int2* __restrict__ ecv, const float* __restrict__ bg,
    hf4* __restrict__ outv, int N) {
  const int wid = threadIdx.x >> 6;
  const int lane = threadIdx.x & 63;
  const int sub = lane >> 5;
  const int ln = lane & 31;
  const int node = blockIdx.x * 8 + wid * 2 + sub;
  if (node >= N) return;
  const hf4 xrh = xr[(long long)node * 32 + ln];
  const float4 avf = ((const float4*)att)[ln];
  hf2 av01, av23;
  av01.x = (_Float16)avf.x; av01.y = (_Float16)avf.y;
  av23.x = (_Float16)avf.z; av23.y = (_Float16)avf.w;
  hf4 c02 = {(_Float16)0.2f, (_Float16)0.2f, (_Float16)0.2f, (_Float16)0.2f};

  // two independent online-softmax states (even/odd 4-batches)
  float m[2] = {-1e30f, -1e30f}, sa[2] = {0.f, 0.f};
  float ax[2] = {0.f, 0.f}, ay[2] = {0.f, 0.f}, az[2] = {0.f, 0.f}, aw[2] = {0.f, 0.f};
  const int start = rowptr[node];
  const int cnt = rowptr[node + 1] - start;
  const int items = cnt + 1;  // + self

  for (int i = 0; i < items; i += 8) {
#pragma unroll
    for (int hset = 0; hset < 2; ++hset) {
      const int base = i + hset * 4;
      if (base < items) {
        float d[4];
        float vx[4], vy[4], vz[4], vw[4];
#pragma unroll
        for (int k = 0; k < 4; ++k) {
          const int idx = base + k;
          const int col = (idx < cnt) ? ecv[start + idx].x : node;
          const hf4 xh = xl[(long long)col * 32 + ln];
          hf4 t = xh + xrh;
          hf4 t2 = t * c02;
#if __has_builtin(__builtin_elementwise_max)
          hf4 lk = __builtin_elementwise_max(t, t2);
#else
          hf4 lk;
          lk.x = t.x > t2.x ? t.x : t2.x; lk.y = t.y > t2.y ? t.y : t2.y;
          lk.z = t.z > t2.z ? t.z : t2.z; lk.w = t.w > t2.w ? t.w : t2.w;
#endif
          hf2 lo; lo.x = lk.x; lo.y = lk.y;
          hf2 hi; hi.x = lk.z; hi.y = lk.w;
#if __has_builtin(__builtin_amdgcn_fdot2)
          d[k] = __builtin_amdgcn_fdot2(lo, av01, __builtin_amdgcn_fdot2(hi, av23, 0.f, false), false);
#else
          d[k] = (float)lk.x * avf.x + (float)lk.y * avf.y +
                 (float)lk.z * avf.z + (float)lk.w * avf.w;
#endif
          vx[k] = (float)xh.x; vy[k] = (float)xh.y;
          vz[k] = (float)xh.z; vw[k] = (float)xh.w;
        }
#pragma unroll
        for (int k = 0; k < 4; ++k) {
          d[k] += __shfl_xor(d[k], 1);
          d[k] += __shfl_xor(d[k], 2);
          d[k] += __shfl_xor(d[k], 4);
          if (base + k >= items) d[k] = -1e30f;   // uniform per node half
        }
        const float mn = fmaxf(fmaxf(fmaxf(d[0], d[1]), fmaxf(d[2], d[3])), m[hset]);
        const float scale = __expf(m[hset] - mn);
        const float p0 = __expf(d[0] - mn), p1 = __expf(d[1] - mn);
        const float p2 = __expf(d[2] - mn), p3 = __expf(d[3] - mn);
        sa[hset] = sa[hset] * scale + ((p0 + p1) + (p2 + p3));
        ax[hset] = ax[hset] * scale + ((p0 * vx[0] + p1 * vx[1]) + (p2 * vx[2] + p3 * vx[3]));
        ay[hset] = ay[hset] * scale + ((p0 * vy[0] + p1 * vy[1]) + (p2 * vy[2] + p3 * vy[3]));
        az[hset] = az[hset] * scale + ((p0 * vz[0] + p1 * vz[1]) + (p2 * vz[2] + p3 * vz[3]));
        aw[hset] = aw[hset] * scale + ((p0 * vw[0] + p1 * vw[1]) + (p2 * vw[2] + p3 * vw[3]));
        m[hset] = mn;
      }
    }
  }
  // merge the two states
  const float mm = fmaxf(m[0], m[1]);
  const float e0 = __expf(m[0] - mm), e1 = __expf(m[1] - mm);
  const float s = sa[0] * e0 + sa[1] * e1;
  const float fx = ax[0] * e0 + ax[1] * e1;
  const float fy = ay[0] * e0 + ay[1] * e1;
  const float fz = az[0] * e0 + az[1] * e1;
  const float fw = aw[0] * e0 + aw[1] * e1;
  const float inv = 1.0f / (s + 1e-16f);
  const float4 b = ((const float4*)bg)[ln];
  hf4 r;
  r.x = (_Float16)fmaxf(fx * inv + b.x, 0.f);
  r.y = (_Float16)fmaxf(fy * inv + b.y, 0.f);
  r.z = (_Float16)fmaxf(fz * inv + b.z, 0.f);
  r.w = (_Float16)fmaxf(fw * inv + b.w, 0.f);
  outv[(long long)node * 32 + ln] = r;
}

// ---------------------------------------------------------------------------

extern "C" void kernel_launch(void* const* d_in, const int* in_sizes, int n_in,
                              void* d_out, int out_size, void* d_ws, size_t ws_size,
                              hipStream_t stream) {
  const float* x  = (const float*)d_in[0];
  const int*   ei = (const int*)d_in[1];
  const float* W1 = (const float*)d_in[2];  const float* b1 = (const float*)d_in[3];
  const float* W2 = (const float*)d_in[4];  const float* b2 = (const float*)d_in[5];
  const float* W3 = (const float*)d_in[6];  const float* b3 = (const float*)d_in[7];
  const float* W4 = (const float*)d_in[8];  const float* b4 = (const float*)d_in[9];
  const float* Wl = (const float*)d_in[10]; const float* Wr = (const float*)d_in[11];
  const float* att= (const float*)d_in[12]; const float* bg = (const float*)d_in[13];
  const float* Wc1= (const float*)d_in[14];
  const float* W5 = (const float*)d_in[15]; const float* b5 = (const float*)d_in[16];
  const float* Wc2= (const float*)d_in[17];
  const float* Wo = (const float*)d_in[18]; const float* bo = (const float*)d_in[19];

  const int N = in_sizes[0] / 300;
  const int E = in_sizes[1] / 2;
  float* out = (float*)d_out;

  const float BETA = 0.04879016416943205f;
  const float OMB  = 1.0f - BETA;

  // ---- workspace carve-up ----
  float* wsf = (float*)d_ws;
  auto alloc = [&](long long nelem) {  // nelem in f32 units
    float* p = wsf; wsf += (nelem + 3) & ~3LL; return p;
  };
  float* dinv   = alloc(N);
  int*   rowptr = (int*)alloc(N + 1);
  int2*  ecv    = (int2*)alloc(2LL * E);                 // packed {col, val}
  _Float16* x1f = (_Float16*)alloc((long long)N * 128);  // N*256 halfs
  _Float16* x2f = (_Float16*)alloc((long long)N * 64);   // N*128 halfs
  _Float16* XH  = (_Float16*)alloc((long long)N * 64);   // xl (N*128 halfs)
  _Float16* XL  = (_Float16*)alloc((long long)N * 64);   // xr (N*128 halfs)
  _Float16* PA  = (_Float16*)alloc((long long)N * 128);  // N*256 halfs
  _Float16* PB  = (_Float16*)alloc((long long)N * 128);
  int*   bsum   = (int*)alloc(64);
  // arena sizing over the 9 packed matrices (Wl|Wr merged at slot 4), 1 plane
  struct WDesc { const float* W; int K, M; };
  WDesc wd[9] = {{W1,300,256},{W2,256,128},{W3,128,64},{W4,64,32},
                 {Wl,32,256} /*merged*/,{Wc1,128,128},{W5,128,256},
                 {Wc2,256,256},{Wo,256,128}};
  long long woff[9], wtot = 0;
  int wkp[9];
  for (int i = 0; i < 9; ++i) {
    wkp[i] = (wd[i].K + 63) & ~63;
    woff[i] = wtot;
    wtot += (long long)wkp[i] * wd[i].M;    // single fp16 plane
  }
  _Float16* warena = (_Float16*)alloc(wtot / 2 + 4);
  // setup-only overlays (CSR build precedes any PA use):
  int* deg  = (int*)PA;
  int* fill = (int*)PA + N;

  const int gemm_grid = (N + 127) / 128;
  auto gemm = [&](int wi, const _Float16* A, const float* bias,
                  const _Float16* aux, float c1, float c2, _Float16* C, _Float16* C2,
                  int MT, int epi) {
    const _Float16* Bhi = warena + woff[wi];
#define GEMM_CASE(MM, EE) \
    if (MT == MM && epi == EE) { \
      gemm_mfma_kernel<MM,EE,0><<<gemm_grid, 256, 0, stream>>>( \
          A, nullptr, Bhi, bias, aux, c1, c2, C, C2, N, wkp[wi]); return; }
    GEMM_CASE(16,0) GEMM_CASE(16,2) GEMM_CASE(16,3)
    GEMM_CASE(8,0)  GEMM_CASE(8,3)
    GEMM_CASE(4,0)  GEMM_CASE(2,0)
#undef GEMM_CASE
  };

  // ---- single-kernel weight packing (writes pads; no arena memset) ----
  {
    PackArgs pa;
    long long cum = 0;
    int di = 0;
    for (int i = 0; i < 9; ++i) {
      if (i == 4) {  // merged Wl | Wr
        pa.d[di] = {Wl, woff[i], cum, 32, 128, 0, 256, wkp[i]};
        cum += (long long)wkp[i] * 128; ++di;
        pa.d[di] = {Wr, woff[i], cum, 32, 128, 128, 256, wkp[i]};
        cum += (long long)wkp[i] * 128; ++di;
      } else {
        pa.d[di] = {wd[i].W, woff[i], cum, wd[i].K, wd[i].M, 0, wd[i].M, wkp[i]};
        cum += (long long)wkp[i] * wd[i].M; ++di;
      }
    }
    pa.n = di;
    pa.total = cum;
    pack_all_kernel<<<(int)((cum + 255) / 256), 256, 0, stream>>>(pa, warena);
  }

  // ---- CSR build (deg/fill overlay PA) ----
  hipMemsetAsync(deg, 0, (size_t)(2 * N) * sizeof(int), stream);
  deg_kernel<<<2048, 256, 0, stream>>>(ei, deg, E);
  dinv_kernel<<<(N + 255) / 256, 256, 0, stream>>>(deg, dinv, rowptr, N);
  {
    int nb = (N + 2047) / 2048;
    scan_block_kernel<<<nb, 256, 0, stream>>>(deg, rowptr + 1, bsum, N);
    scan_small_kernel<<<1, 64, 0, stream>>>(bsum, nb);
    scan_add_kernel<<<nb, 256, 0, stream>>>(rowptr + 1, bsum, N);
  }
  fill_csr_kernel<<<2048, 256, 0, stream>>>(ei, dinv, rowptr, fill, ecv, E);

  const hf8* PA8 = (const hf8*)PA;
  const hf8* PB8 = (const hf8*)PB;

  // ---- layer 1: x1 = relu(prop(x@W1)+b1) -> x1f (f32 A, in-register split) ----
  gemm_mfma_xf32_kernel<16><<<gemm_grid, 256, 0, stream>>>(
      x, warena + woff[0], PA, N, wkp[0], 300);
  prop_csr_kernel<256,2,4,32,0><<<(N + 7) / 8, 256, 0, stream>>>(
      PA8, rowptr, ecv, dinv, b1, nullptr, nullptr, (hf8*)x1f, N);

  // ---- layer 2: x2f ----
  gemm(1, x1f, nullptr, nullptr, 0, 0, PA, nullptr, 8, 0);
  prop_csr_kernel<128,2,4,16,0><<<(N + 15) / 16, 256, 0, stream>>>(
      PA8, rowptr, ecv, dinv, b2, nullptr, nullptr, (hf8*)x2f, N);

  // ---- layer 3 ----
  gemm(2, x2f, nullptr, nullptr, 0, 0, PA, nullptr, 4, 0);
  prop_csr_kernel<64,2,4,8,0><<<(N + 31) / 32, 256, 0, stream>>>(
      PA8, rowptr, ecv, dinv, b3, nullptr, nullptr, (hf8*)PB, N);

  // ---- layer 4: output padded in-kernel to N x 64 halfs (Kp=64) ----
  gemm(3, PB, nullptr, nullptr, 0, 0, PA, nullptr, 2, 0);
  prop_csr_kernel<32,2,4,8,1><<<(N + 63) / 64, 256, 0, stream>>>(
      PA8, rowptr, ecv, dinv, b4, nullptr, nullptr, (hf8*)PB, N);

  // ---- GATv2: merged Wl|Wr GEMM with split store -> xl (XH), xr (XL) ----
  gemm(4, PB, nullptr, nullptr, 0, 0, XH, XL, 16, 0);
  gat_fused_kernel<<<(N + 7) / 8, 256, 0, stream>>>(
      (const hf4*)XH, (const hf4*)XL, att, rowptr, ecv, bg, (hf4*)PB, N);
  // x3 (fp16 N x 128) in PB

  // ---- GCN2 #1: h = 0.5*prop(x3)+0.5*x2f -> PA; res = relu(OMB*h+BETA*h@Wc1) ----
  prop_csr_kernel<128,3,4,16,0><<<(N + 15) / 16, 256, 0, stream>>>(
      PB8, rowptr, ecv, dinv, nullptr, (const hf8*)x2f, nullptr, (hf8*)PA, N);
  gemm(5, PA, nullptr, PA, OMB, BETA, PB, nullptr, 8, 3);   // res in PB

  // ---- W5 layer: relu(prop(res)@W5+b5) ----
  prop_csr_kernel<128,0,4,16,0><<<(N + 15) / 16, 256, 0, stream>>>(
      PB8, rowptr, ecv, dinv, nullptr, nullptr, nullptr, (hf8*)PA, N);
  gemm(6, PA, b5, nullptr, 0, 0, PB, nullptr, 16, 2);       // y5 in PB

  // ---- GCN2 #2: h2 = 0.5*prop(y5)+0.5*x1f -> PA; res2 = relu(OMB*h2+BETA*h2@Wc2) ----
  prop_csr_kernel<256,3,4,32,0><<<(N + 7) / 8, 256, 0, stream>>>(
      PB8, rowptr, ecv, dinv, nullptr, (const hf8*)x1f, nullptr, (hf8*)PA, N);
  gemm(7, PA, nullptr, PA, OMB, BETA, PB, nullptr, 16, 3);  // res2 in PB

  // ---- final: prop(res2@Wo) + bo -> f32 out ----
  gemm(8, PB, nullptr, nullptr, 0, 0, PA, nullptr, 8, 0);
  prop_csr_kernel<128,1,1,16,0><<<(N + 15) / 16, 256, 0, stream>>>(
      PA8, rowptr, ecv, dinv, bo, nullptr, (float4*)out, nullptr, N);
}

// Round 16
// 710.555 us; speedup vs baseline: 1.0100x; 1.0100x over previous
//
#include <hip/hip_runtime.h>
#include <math.h>

// ---------------------------------------------------------------------------
// GraphAutoEncoder forward on MI355X. Round 16 = round 15 with the GAT
// reverted to round-13's single-state 4-edge-batch online softmax (the
// dual-state variant was the hidden ~20us regression masking the conv_x
// fusion win). GEMM0 keeps in-register f32->fp16 hi/lo split.
//   - single-plane fp16 weights, int2 CSR, hf8 gather props
// ---------------------------------------------------------------------------

typedef __attribute__((ext_vector_type(4))) float f32x4;
typedef _Float16 hf2 __attribute__((ext_vector_type(2)));
typedef _Float16 hf4 __attribute__((ext_vector_type(4)));
typedef _Float16 hf8 __attribute__((ext_vector_type(8)));

// ---------------- CSR build ----------------

__global__ void deg_kernel(const int* __restrict__ ei, int* __restrict__ deg, int E) {
  int i = blockIdx.x * blockDim.x + threadIdx.x;
  int stride = gridDim.x * blockDim.x;
  for (; i < E; i += stride) atomicAdd(&deg[ei[E + i]], 1);
}

__global__ void dinv_kernel(const int* __restrict__ deg, float* __restrict__ dinv,
                            int* __restrict__ rowptr, int N) {
  int i = blockIdx.x * blockDim.x + threadIdx.x;
  if (i == 0) rowptr[0] = 0;
  if (i < N) dinv[i] = rsqrtf((float)(deg[i] + 1));  // +1 self-loop
}

__global__ __launch_bounds__(256) void scan_block_kernel(const int* __restrict__ in,
                                                         int* __restrict__ out,
                                                         int* __restrict__ bsum, int n) {
  __shared__ int lds[256];
  const int base = blockIdx.x * 2048;
  const int tid = threadIdx.x;
  int v[8];
  int s = 0;
#pragma unroll
  for (int k = 0; k < 8; ++k) {
    int idx = base + tid * 8 + k;
    v[k] = (idx < n) ? in[idx] : 0;
    s += v[k];
  }
  lds[tid] = s;
  __syncthreads();
  for (int off = 1; off < 256; off <<= 1) {
    int t = (tid >= off) ? lds[tid - off] : 0;
    __syncthreads();
    lds[tid] += t;
    __syncthreads();
  }
  int run = (tid > 0) ? lds[tid - 1] : 0;
#pragma unroll
  for (int k = 0; k < 8; ++k) {
    int idx = base + tid * 8 + k;
    run += v[k];
    if (idx < n) out[idx] = run;
  }
  if (tid == 255) bsum[blockIdx.x] = lds[255];
}

__global__ void scan_small_kernel(int* bsum, int nb) {
  if (threadIdx.x == 0 && blockIdx.x == 0) {
    int run = 0;
    for (int i = 0; i < nb; ++i) { int t = bsum[i]; bsum[i] = run; run += t; }
  }
}

__global__ __launch_bounds__(256) void scan_add_kernel(int* __restrict__ out,
                                                       const int* __restrict__ bsum, int n) {
  int idx = blockIdx.x * 2048 + threadIdx.x;
  const int add = bsum[blockIdx.x];
#pragma unroll
  for (int k = 0; k < 8; ++k, idx += 256)
    if (idx < n) out[idx] += add;
}

// one random 8B store per edge (col + val bits packed)
__global__ void fill_csr_kernel(const int* __restrict__ ei, const float* __restrict__ dinv,
                                const int* __restrict__ rowptr, int* __restrict__ fill,
                                int2* __restrict__ ecv, int E) {
  int e = blockIdx.x * blockDim.x + threadIdx.x;
  int stride = gridDim.x * blockDim.x;
  for (; e < E; e += stride) {
    int s = ei[e], t = ei[E + e];
    int pos = rowptr[t] + atomicAdd(&fill[t], 1);
    ecv[pos] = make_int2(s, __float_as_int(dinv[s] * dinv[t]));
  }
}

// ---------------- propagation (CSR gather hf8, f32 accumulate) -------------
// EPI: 0 none | 1 +bias(f32) | 2 relu(+bias f32) | 3 0.5*acc+0.5*bx16
// OUT: 1 = f32 out | 4 = fp16 pf.  OS = output row stride in hf8 units.
// PAD: write zero hf8 at pf[node*OS + TPN + q] (layer-4 Kp pad)
template <int D, int EPI, int OUT, int OS, int PAD>
__global__ __launch_bounds__(256) void prop_csr_kernel(
    const hf8* __restrict__ h, const int* __restrict__ rowptr,
    const int2* __restrict__ ecv, const float* __restrict__ dinv,
    const float* __restrict__ bias, const hf8* __restrict__ bx16,
    float4* __restrict__ out, hf8* __restrict__ pf, int N) {
  constexpr int TPN = D / 8;
  constexpr int NPB = 256 / TPN;
  const int node = blockIdx.x * NPB + threadIdx.x / TPN;
  const int q = threadIdx.x % TPN;
  if (node >= N) return;
  const int start = rowptr[node], end = rowptr[node + 1];
  float acc[8] = {};
  int j = start;
  for (; j + 1 < end; j += 2) {
    const int2 e0 = ecv[j], e1 = ecv[j + 1];
    const float v0 = __int_as_float(e0.y), v1 = __int_as_float(e1.y);
    const hf8 a = h[(long long)e0.x * TPN + q];
    const hf8 b = h[(long long)e1.x * TPN + q];
#pragma unroll
    for (int k = 0; k < 8; ++k) acc[k] += v0 * (float)a[k] + v1 * (float)b[k];
  }
  if (j < end) {
    const int2 e0 = ecv[j];
    const float v = __int_as_float(e0.y);
    const hf8 a = h[(long long)e0.x * TPN + q];
#pragma unroll
    for (int k = 0; k < 8; ++k) acc[k] += v * (float)a[k];
  }
  {
    const float di = dinv[node];
    const float sv = di * di;
    const hf8 a = h[(long long)node * TPN + q];
#pragma unroll
    for (int k = 0; k < 8; ++k) acc[k] += sv * (float)a[k];
  }
  float r[8];
  if (EPI == 0) {
#pragma unroll
    for (int k = 0; k < 8; ++k) r[k] = acc[k];
  } else if (EPI == 1 || EPI == 2) {
    float4 b0 = ((const float4*)bias)[2 * q];
    float4 b1 = ((const float4*)bias)[2 * q + 1];
    r[0] = acc[0] + b0.x; r[1] = acc[1] + b0.y; r[2] = acc[2] + b0.z; r[3] = acc[3] + b0.w;
    r[4] = acc[4] + b1.x; r[5] = acc[5] + b1.y; r[6] = acc[6] + b1.z; r[7] = acc[7] + b1.w;
    if (EPI == 2) {
#pragma unroll
      for (int k = 0; k < 8; ++k) r[k] = fmaxf(r[k], 0.f);
    }
  } else {  // EPI == 3
    hf8 x0 = bx16[(long long)node * TPN + q];
#pragma unroll
    for (int k = 0; k < 8; ++k) r[k] = 0.5f * (acc[k] + (float)x0[k]);
  }
  if (OUT == 1) {
    float4 o0 = make_float4(r[0], r[1], r[2], r[3]);
    float4 o1 = make_float4(r[4], r[5], r[6], r[7]);
    out[(long long)node * (D / 4) + 2 * q] = o0;
    out[(long long)node * (D / 4) + 2 * q + 1] = o1;
  } else {
    hf8 p;
#pragma unroll
    for (int k = 0; k < 8; ++k) p[k] = (_Float16)r[k];
    pf[(long long)node * OS + q] = p;
    if (PAD) {
      hf8 z = {0, 0, 0, 0, 0, 0, 0, 0};
      pf[(long long)node * OS + TPN + q] = z;
    }
  }
}

// ---------------- single-kernel weight packing (single fp16 plane) ---------
struct PackDesc {
  const float* W;
  long long off;   // arena offset (halfs)
  long long cum;   // cumulative element start
  int K, Msrc, moff, Mtot, Kp;
};
struct PackArgs {
  PackDesc d[10];
  int n;
  long long total;
};

__global__ void pack_all_kernel(PackArgs pa, _Float16* __restrict__ arena) {
  long long i = (long long)blockIdx.x * blockDim.x + threadIdx.x;
  const long long stride = (long long)gridDim.x * blockDim.x;
  for (; i < pa.total; i += stride) {
    int wi = 0;
    while (wi + 1 < pa.n && i >= pa.d[wi + 1].cum) ++wi;
    const PackDesc dd = pa.d[wi];
    long long li = i - dd.cum;          // in [0, Kp*Msrc)
    int k = (int)(li / dd.Msrc);
    int m0 = (int)(li % dd.Msrc);
    int m = dd.moff + m0;
    float v = (k < dd.K) ? dd.W[(long long)k * dd.Msrc + m0] : 0.f;
    const int MT = dd.Mtot >> 4;
    int chunkk = k >> 6, kin = k & 63;
    int s2 = (kin >> 5) & 1, kin2 = kin & 31;
    int lane = ((kin2 >> 3) << 4) | (m & 15);
    int jj = kin2 & 7, t = m >> 4;
    long long idx = ((((long long)(chunkk * MT + t) * 2 + s2) * 64 + lane) * 8 + jj);
    arena[dd.off + idx] = (_Float16)v;
  }
}

// ---------------- MFMA GEMM (f16, single-product) --------------------------
// EPI: 0 none | 2 bias+relu | 3 relu(c1*aux + c2*acc), aux fp16
// Cf2 != nullptr: split store, cols [0,M/2) -> Cf, [M/2,M) -> Cf2 (stride M/2)
template <int MT, int EPI>
__global__ __launch_bounds__(256) void gemm_mfma_kernel(
    const _Float16* __restrict__ A, const _Float16* __restrict__ Bhi,
    const float* __restrict__ bias, const _Float16* __restrict__ aux,
    float c1, float c2, _Float16* __restrict__ Cf, _Float16* __restrict__ Cf2,
    int N, int Kp) {
  constexpr int M = MT * 16;
  constexpr int chunk = M * 64;
  __shared__ _Float16 lds[chunk];
  const int tid = threadIdx.x;
  const int w = tid >> 6, l = tid & 63;
  const int lr = l & 15, lh = l >> 4;
  const int rowbase = blockIdx.x * 128 + w * 32;
  int r0 = rowbase + lr;      if (r0 >= N) r0 = N - 1;
  int r1 = rowbase + 16 + lr; if (r1 >= N) r1 = N - 1;

  f32x4 acc[2][MT] = {};
  const int nchunks = Kp >> 6;
  const int n16 = chunk / 8;

  for (int c = 0; c < nchunks; ++c) {
    const uint4* srcH = (const uint4*)(Bhi + (long long)c * chunk);
    __syncthreads();
    for (int i = tid; i < n16; i += 256) ((uint4*)lds)[i] = srcH[i];
    __syncthreads();
#pragma unroll
    for (int s = 0; s < 2; ++s) {
      const long long abase = (long long)c * 64 + s * 32 + lh * 8;
      hf8 a0 = *(const hf8*)(A + (long long)r0 * Kp + abase);
      hf8 a1 = *(const hf8*)(A + (long long)r1 * Kp + abase);
#pragma unroll
      for (int t = 0; t < MT; ++t) {
        const int boff = ((t * 2 + s) * 64 + l) * 8;
        hf8 bh = *(const hf8*)(lds + boff);
        acc[0][t] = __builtin_amdgcn_mfma_f32_16x16x32_f16(a0, bh, acc[0][t], 0, 0, 0);
        acc[1][t] = __builtin_amdgcn_mfma_f32_16x16x32_f16(a1, bh, acc[1][t], 0, 0, 0);
      }
    }
  }
  // epilogue: two 64-row halves through the same LDS buffer, coalesced stores
#pragma unroll
  for (int rt = 0; rt < 2; ++rt) {
    __syncthreads();
#pragma unroll
    for (int t = 0; t < MT; ++t) {
      const int col = t * 16 + lr;
      float b = (EPI == 2) ? bias[col] : 0.f;
#pragma unroll
      for (int j = 0; j < 4; ++j) {
        int row = rowbase + rt * 16 + lh * 4 + j;
        float v;
        if (EPI == 3) {
          int ar = row < N ? row : N - 1;
          v = fmaxf(c1 * (float)aux[(long long)ar * M + col] + c2 * acc[rt][t][j], 0.f);
        } else {
          v = acc[rt][t][j] + b;
          if (EPI == 2) v = fmaxf(v, 0.f);
        }
        lds[(w * 16 + lh * 4 + j) * M + col] = (_Float16)v;
      }
    }
    __syncthreads();
    constexpr int slots = 64 * M / 8;
    const uint4* ls = (const uint4*)lds;
    for (int i = tid; i < slots; i += 256) {
      int r = i / (M / 8);
      int c8 = i % (M / 8);
      int grow = blockIdx.x * 128 + (r >> 4) * 32 + rt * 16 + (r & 15);
      if (grow < N) {
        if (Cf2) {
          if (c8 < M / 16) *(uint4*)(Cf  + (long long)grow * (M / 2) + c8 * 8) = ls[i];
          else             *(uint4*)(Cf2 + (long long)grow * (M / 2) + (c8 - M / 16) * 8) = ls[i];
        } else {
          *(uint4*)(Cf + (long long)grow * M + c8 * 8) = ls[i];
        }
      }
    }
  }
}

// ---------------- GEMM0: A = f32 x[N x 300], in-register hi/lo split -------
template <int MT>
__global__ __launch_bounds__(256) void gemm_mfma_xf32_kernel(
    const float* __restrict__ A, const _Float16* __restrict__ Bhi,
    _Float16* __restrict__ Cf, int N, int Kp, int Ksrc) {
  constexpr int M = MT * 16;
  constexpr int chunk = M * 64;
  __shared__ _Float16 lds[chunk];
  const int tid = threadIdx.x;
  const int w = tid >> 6, l = tid & 63;
  const int lr = l & 15, lh = l >> 4;
  const int rowbase = blockIdx.x * 128 + w * 32;
  int r0 = rowbase + lr;      if (r0 >= N) r0 = N - 1;
  int r1 = rowbase + 16 + lr; if (r1 >= N) r1 = N - 1;

  f32x4 acc[2][MT] = {};
  const int nchunks = Kp >> 6;
  const int n16 = chunk / 8;

  for (int c = 0; c < nchunks; ++c) {
    const uint4* srcH = (const uint4*)(Bhi + (long long)c * chunk);
    __syncthreads();
    for (int i = tid; i < n16; i += 256) ((uint4*)lds)[i] = srcH[i];
    __syncthreads();
#pragma unroll
    for (int s = 0; s < 2; ++s) {
      const int abase = c * 64 + s * 32 + lh * 8;
      float4 z4 = make_float4(0.f, 0.f, 0.f, 0.f);
      float4 v0a = (abase + 4 <= Ksrc) ? *(const float4*)(A + (long long)r0 * Ksrc + abase) : z4;
      float4 v0b = (abase + 8 <= Ksrc) ? *(const float4*)(A + (long long)r0 * Ksrc + abase + 4) : z4;
      float4 v1a = (abase + 4 <= Ksrc) ? *(const float4*)(A + (long long)r1 * Ksrc + abase) : z4;
      float4 v1b = (abase + 8 <= Ksrc) ? *(const float4*)(A + (long long)r1 * Ksrc + abase + 4) : z4;
      float f0[8] = {v0a.x, v0a.y, v0a.z, v0a.w, v0b.x, v0b.y, v0b.z, v0b.w};
      float f1[8] = {v1a.x, v1a.y, v1a.z, v1a.w, v1b.x, v1b.y, v1b.z, v1b.w};
      hf8 a0, a0l, a1, a1l;
#pragma unroll
      for (int j = 0; j < 8; ++j) {
        a0[j] = (_Float16)f0[j]; a0l[j] = (_Float16)(f0[j] - (float)a0[j]);
        a1[j] = (_Float16)f1[j]; a1l[j] = (_Float16)(f1[j] - (float)a1[j]);
      }
#pragma unroll
      for (int t = 0; t < MT; ++t) {
        const int boff = ((t * 2 + s) * 64 + l) * 8;
        hf8 bh = *(const hf8*)(lds + boff);
        acc[0][t] = __builtin_amdgcn_mfma_f32_16x16x32_f16(a0, bh, acc[0][t], 0, 0, 0);
        acc[1][t] = __builtin_amdgcn_mfma_f32_16x16x32_f16(a1, bh, acc[1][t], 0, 0, 0);
        acc[0][t] = __builtin_amdgcn_mfma_f32_16x16x32_f16(a0l, bh, acc[0][t], 0, 0, 0);
        acc[1][t] = __builtin_amdgcn_mfma_f32_16x16x32_f16(a1l, bh, acc[1][t], 0, 0, 0);
      }
    }
  }
  // epilogue (EPI=0), two 64-row halves
#pragma unroll
  for (int rt = 0; rt < 2; ++rt) {
    __syncthreads();
#pragma unroll
    for (int t = 0; t < MT; ++t) {
      const int col = t * 16 + lr;
#pragma unroll
      for (int j = 0; j < 4; ++j)
        lds[(w * 16 + lh * 4 + j) * M + col] = (_Float16)acc[rt][t][j];
    }
    __syncthreads();
    constexpr int slots = 64 * M / 8;
    const uint4* ls = (const uint4*)lds;
    for (int i = tid; i < slots; i += 256) {
      int r = i / (M / 8);
      int c8 = i % (M / 8);
      int grow = blockIdx.x * 128 + (r >> 4) * 32 + rt * 16 + (r & 15);
      if (grow < N) *(uint4*)(Cf + (long long)grow * M + c8 * 8) = ls[i];
    }
  }
}

// ---------------- fused GATv2 (single-state online softmax, 4-edge batch,
// 2 nodes/wave, hf4/lane) — round-13 version (measured 54us) ---------------
__global__ __launch_bounds__(256) void gat_fused_kernel(
    const hf4* __restrict__ xl, const hf4* __restrict__ xr,
    const float* __restrict__ att, const int* __restrict__ rowptr,
    const int2* __restrict__ ecv, const float* __restrict__ bg,
    hf4* __restrict__ outv, int N) {
  const int wid = threadIdx.x >> 6;
  const int lane = threadIdx.x & 63;
  const int sub = lane >> 5;
  const int ln = lane & 31;
  const int node = blockIdx.x * 8 + wid * 2 + sub;
  if (node >= N) return;
  const hf4 xrh = xr[(long long)node * 32 + ln];
  const float4 avf = ((const float4*)att)[ln];
  hf2 av01, av23;
  av01.x = (_Float16)avf.x; av01.y = (_Float16)avf.y;
  av23.x = (_Float16)avf.z; av23.y = (_Float16)avf.w;
  hf4 c02 = {(_Float16)0.2f, (_Float16)0.2f, (_Float16)0.2f, (_Float16)0.2f};

  float m = -1e30f, s = 0.f;
  float ax = 0.f, ay = 0.f, az = 0.f, aw = 0.f;
  const int start = rowptr[node];
  const int cnt = rowptr[node + 1] - start;
  const int items = cnt + 1;  // + self

  for (int i = 0; i < items; i += 4) {
    float d[4];
    float vx[4], vy[4], vz[4], vw[4];
#pragma unroll
    for (int k = 0; k < 4; ++k) {
      const int idx = i + k;
      const int col = (idx < cnt) ? ecv[start + idx].x : node;
      const hf4 xh = xl[(long long)col * 32 + ln];
      hf4 t = xh + xrh;
      hf4 t2 = t * c02;
#if __has_builtin(__builtin_elementwise_max)
      hf4 lk = __builtin_elementwise_max(t, t2);
#else
      hf4 lk;
      lk.x = t.x > t2.x ? t.x : t2.x; lk.y = t.y > t2.y ? t.y : t2.y;
      lk.z = t.z > t2.z ? t.z : t2.z; lk.w = t.w > t2.w ? t.w : t2.w;
#endif
      hf2 lo; lo.x = lk.x; lo.y = lk.y;
      hf2 hi; hi.x = lk.z; hi.y = lk.w;
#if __has_builtin(__builtin_amdgcn_fdot2)
      d[k] = __builtin_amdgcn_fdot2(lo, av01, __builtin_amdgcn_fdot2(hi, av23, 0.f, false), false);
#else
      d[k] = (float)lk.x * avf.x + (float)lk.y * avf.y +
             (float)lk.z * avf.z + (float)lk.w * avf.w;
#endif
      vx[k] = (float)xh.x; vy[k] = (float)xh.y;
      vz[k] = (float)xh.z; vw[k] = (float)xh.w;
    }
#pragma unroll
    for (int k = 0; k < 4; ++k) {
      d[k] += __shfl_xor(d[k], 1);
      d[k] += __shfl_xor(d[k], 2);
      d[k] += __shfl_xor(d[k], 4);
      if (i + k >= items) d[k] = -1e30f;   // uniform per node half
    }
    const float mn = fmaxf(fmaxf(fmaxf(d[0], d[1]), fmaxf(d[2], d[3])), m);
    const float scale = __expf(m - mn);
    const float p0 = __expf(d[0] - mn), p1 = __expf(d[1] - mn);
    const float p2 = __expf(d[2] - mn), p3 = __expf(d[3] - mn);
    s = s * scale + ((p0 + p1) + (p2 + p3));
    ax = ax * scale + ((p0 * vx[0] + p1 * vx[1]) + (p2 * vx[2] + p3 * vx[3]));
    ay = ay * scale + ((p0 * vy[0] + p1 * vy[1]) + (p2 * vy[2] + p3 * vy[3]));
    az = az * scale + ((p0 * vz[0] + p1 * vz[1]) + (p2 * vz[2] + p3 * vz[3]));
    aw = aw * scale + ((p0 * vw[0] + p1 * vw[1]) + (p2 * vw[2] + p3 * vw[3]));
    m = mn;
  }
  const float inv = 1.0f / (s + 1e-16f);
  const float4 b = ((const float4*)bg)[ln];
  hf4 r;
  r.x = (_Float16)fmaxf(ax * inv + b.x, 0.f);
  r.y = (_Float16)fmaxf(ay * inv + b.y, 0.f);
  r.z = (_Float16)fmaxf(az * inv + b.z, 0.f);
  r.w = (_Float16)fmaxf(aw * inv + b.w, 0.f);
  outv[(long long)node * 32 + ln] = r;
}

// ---------------------------------------------------------------------------

extern "C" void kernel_launch(void* const* d_in, const int* in_sizes, int n_in,
                              void* d_out, int out_size, void* d_ws, size_t ws_size,
                              hipStream_t stream) {
  const float* x  = (const float*)d_in[0];
  const int*   ei = (const int*)d_in[1];
  const float* W1 = (const float*)d_in[2];  const float* b1 = (const float*)d_in[3];
  const float* W2 = (const float*)d_in[4];  const float* b2 = (const float*)d_in[5];
  const float* W3 = (const float*)d_in[6];  const float* b3 = (const float*)d_in[7];
  const float* W4 = (const float*)d_in[8];  const float* b4 = (const float*)d_in[9];
  const float* Wl = (const float*)d_in[10]; const float* Wr = (const float*)d_in[11];
  const float* att= (const float*)d_in[12]; const float* bg = (const float*)d_in[13];
  const float* Wc1= (const float*)d_in[14];
  const float* W5 = (const float*)d_in[15]; const float* b5 = (const float*)d_in[16];
  const float* Wc2= (const float*)d_in[17];
  const float* Wo = (const float*)d_in[18]; const float* bo = (const float*)d_in[19];

  const int N = in_sizes[0] / 300;
  const int E = in_sizes[1] / 2;
  float* out = (float*)d_out;

  const float BETA = 0.04879016416943205f;
  const float OMB  = 1.0f - BETA;

  // ---- workspace carve-up ----
  float* wsf = (float*)d_ws;
  auto alloc = [&](long long nelem) {  // nelem in f32 units
    float* p = wsf; wsf += (nelem + 3) & ~3LL; return p;
  };
  float* dinv   = alloc(N);
  int*   rowptr = (int*)alloc(N + 1);
  int2*  ecv    = (int2*)alloc(2LL * E);                 // packed {col, val}
  _Float16* x1f = (_Float16*)alloc((long long)N * 128);  // N*256 halfs
  _Float16* x2f = (_Float16*)alloc((long long)N * 64);   // N*128 halfs
  _Float16* XH  = (_Float16*)alloc((long long)N * 64);   // xl (N*128 halfs)
  _Float16* XL  = (_Float16*)alloc((long long)N * 64);   // xr (N*128 halfs)
  _Float16* PA  = (_Float16*)alloc((long long)N * 128);  // N*256 halfs
  _Float16* PB  = (_Float16*)alloc((long long)N * 128);
  int*   bsum   = (int*)alloc(64);
  // arena sizing over the 9 packed matrices (Wl|Wr merged at slot 4), 1 plane
  struct WDesc { const float* W; int K, M; };
  WDesc wd[9] = {{W1,300,256},{W2,256,128},{W3,128,64},{W4,64,32},
                 {Wl,32,256} /*merged*/,{Wc1,128,128},{W5,128,256},
                 {Wc2,256,256},{Wo,256,128}};
  long long woff[9], wtot = 0;
  int wkp[9];
  for (int i = 0; i < 9; ++i) {
    wkp[i] = (wd[i].K + 63) & ~63;
    woff[i] = wtot;
    wtot += (long long)wkp[i] * wd[i].M;    // single fp16 plane
  }
  _Float16* warena = (_Float16*)alloc(wtot / 2 + 4);
  // setup-only overlays (CSR build precedes any PA use):
  int* deg  = (int*)PA;
  int* fill = (int*)PA + N;

  const int gemm_grid = (N + 127) / 128;
  auto gemm = [&](int wi, const _Float16* A, const float* bias,
                  const _Float16* aux, float c1, float c2, _Float16* C, _Float16* C2,
                  int MT, int epi) {
    const _Float16* Bhi = warena + woff[wi];
#define GEMM_CASE(MM, EE) \
    if (MT == MM && epi == EE) { \
      gemm_mfma_kernel<MM,EE><<<gemm_grid, 256, 0, stream>>>( \
          A, Bhi, bias, aux, c1, c2, C, C2, N, wkp[wi]); return; }
    GEMM_CASE(16,0) GEMM_CASE(16,2) GEMM_CASE(16,3)
    GEMM_CASE(8,0)  GEMM_CASE(8,3)
    GEMM_CASE(4,0)  GEMM_CASE(2,0)
#undef GEMM_CASE
  };

  // ---- single-kernel weight packing (writes pads; no arena memset) ----
  {
    PackArgs pa;
    long long cum = 0;
    int di = 0;
    for (int i = 0; i < 9; ++i) {
      if (i == 4) {  // merged Wl | Wr
        pa.d[di] = {Wl, woff[i], cum, 32, 128, 0, 256, wkp[i]};
        cum += (long long)wkp[i] * 128; ++di;
        pa.d[di] = {Wr, woff[i], cum, 32, 128, 128, 256, wkp[i]};
        cum += (long long)wkp[i] * 128; ++di;
      } else {
        pa.d[di] = {wd[i].W, woff[i], cum, wd[i].K, wd[i].M, 0, wd[i].M, wkp[i]};
        cum += (long long)wkp[i] * wd[i].M; ++di;
      }
    }
    pa.n = di;
    pa.total = cum;
    pack_all_kernel<<<(int)((cum + 255) / 256), 256, 0, stream>>>(pa, warena);
  }

  // ---- CSR build (deg/fill overlay PA) ----
  hipMemsetAsync(deg, 0, (size_t)(2 * N) * sizeof(int), stream);
  deg_kernel<<<2048, 256, 0, stream>>>(ei, deg, E);
  dinv_kernel<<<(N + 255) / 256, 256, 0, stream>>>(deg, dinv, rowptr, N);
  {
    int nb = (N + 2047) / 2048;
    scan_block_kernel<<<nb, 256, 0, stream>>>(deg, rowptr + 1, bsum, N);
    scan_small_kernel<<<1, 64, 0, stream>>>(bsum, nb);
    scan_add_kernel<<<nb, 256, 0, stream>>>(rowptr + 1, bsum, N);
  }
  fill_csr_kernel<<<2048, 256, 0, stream>>>(ei, dinv, rowptr, fill, ecv, E);

  const hf8* PA8 = (const hf8*)PA;
  const hf8* PB8 = (const hf8*)PB;

  // ---- layer 1: x1 = relu(prop(x@W1)+b1) -> x1f (f32 A, in-register split) ----
  gemm_mfma_xf32_kernel<16><<<gemm_grid, 256, 0, stream>>>(
      x, warena + woff[0], PA, N, wkp[0], 300);
  prop_csr_kernel<256,2,4,32,0><<<(N + 7) / 8, 256, 0, stream>>>(
      PA8, rowptr, ecv, dinv, b1, nullptr, nullptr, (hf8*)x1f, N);

  // ---- layer 2: x2f ----
  gemm(1, x1f, nullptr, nullptr, 0, 0, PA, nullptr, 8, 0);
  prop_csr_kernel<128,2,4,16,0><<<(N + 15) / 16, 256, 0, stream>>>(
      PA8, rowptr, ecv, dinv, b2, nullptr, nullptr, (hf8*)x2f, N);

  // ---- layer 3 ----
  gemm(2, x2f, nullptr, nullptr, 0, 0, PA, nullptr, 4, 0);
  prop_csr_kernel<64,2,4,8,0><<<(N + 31) / 32, 256, 0, stream>>>(
      PA8, rowptr, ecv, dinv, b3, nullptr, nullptr, (hf8*)PB, N);

  // ---- layer 4: output padded in-kernel to N x 64 halfs (Kp=64) ----
  gemm(3, PB, nullptr, nullptr, 0, 0, PA, nullptr, 2, 0);
  prop_csr_kernel<32,2,4,8,1><<<(N + 63) / 64, 256, 0, stream>>>(
      PA8, rowptr, ecv, dinv, b4, nullptr, nullptr, (hf8*)PB, N);

  // ---- GATv2: merged Wl|Wr GEMM with split store -> xl (XH), xr (XL) ----
  gemm(4, PB, nullptr, nullptr, 0, 0, XH, XL, 16, 0);
  gat_fused_kernel<<<(N + 7) / 8, 256, 0, stream>>>(
      (const hf4*)XH, (const hf4*)XL, att, rowptr, ecv, bg, (hf4*)PB, N);
  // x3 (fp16 N x 128) in PB

  // ---- GCN2 #1: h = 0.5*prop(x3)+0.5*x2f -> PA; res = relu(OMB*h+BETA*h@Wc1) ----
  prop_csr_kernel<128,3,4,16,0><<<(N + 15) / 16, 256, 0, stream>>>(
      PB8, rowptr, ecv, dinv, nullptr, (const hf8*)x2f, nullptr, (hf8*)PA, N);
  gemm(5, PA, nullptr, PA, OMB, BETA, PB, nullptr, 8, 3);   // res in PB

  // ---- W5 layer: relu(prop(res)@W5+b5) ----
  prop_csr_kernel<128,0,4,16,0><<<(N + 15) / 16, 256, 0, stream>>>(
      PB8, rowptr, ecv, dinv, nullptr, nullptr, nullptr, (hf8*)PA, N);
  gemm(6, PA, b5, nullptr, 0, 0, PB, nullptr, 16, 2);       // y5 in PB

  // ---- GCN2 #2: h2 = 0.5*prop(y5)+0.5*x1f -> PA; res2 = relu(OMB*h2+BETA*h2@Wc2) ----
  prop_csr_kernel<256,3,4,32,0><<<(N + 7) / 8, 256, 0, stream>>>(
      PB8, rowptr, ecv, dinv, nullptr, (const hf8*)x1f, nullptr, (hf8*)PA, N);
  gemm(7, PA, nullptr, PA, OMB, BETA, PB, nullptr, 16, 3);  // res2 in PB

  // ---- final: prop(res2@Wo) + bo -> f32 out ----
  gemm(8, PB, nullptr, nullptr, 0, 0, PA, nullptr, 8, 0);
  prop_csr_kernel<128,1,1,16,0><<<(N + 15) / 16, 256, 0, stream>>>(
      PA8, rowptr, ecv, dinv, bo, nullptr, (float4*)out, nullptr, N);
}